// Round 14
// baseline (582.491 us; speedup 1.0000x reference)
//
#include <hip/hip_runtime.h>
#include <math.h>

// ---------------- problem constants ----------------
#define V_VOX 12000
#define T_PTS 35
#define DD 10
#define HH 200
#define WW 176
#define EPSV 1e-5f

#define DP 12
#define HP 202
#define WP 178
#define PPLN (HP * WP)          // 35956 padded plane pixels
#define PVOX (DP * PPLN)        // 431472 padded volume pixels
#define NPIX (DD * HH * WW)     // 352000
#define HWPIX (HH * WW)         // 35200

typedef _Float16 half_t;
typedef _Float16 f16x8 __attribute__((ext_vector_type(8)));
typedef float f32x4 __attribute__((ext_vector_type(4)));

// ---------------- workspace layout (BYTE offsets, all 256-aligned) ----------------
#define WPA_OFF 0           // 27*1*4*512 halves = 110592 B
#define WPB_OFF 110592      // 27*2*4*512 halves = 221184 B
#define WPR1_OFF 331776     // 9*2*8*512 halves = 147456 B
#define STATS_OFF 479232    // 1024 floats
#define FEATS_OFF 483328    // 12000*32 f32 = 1536000 B
#define VOLP_OFF 2019328    // PVOX*32 halves = 27614208 B
#define X1P_OFF 29633536    // 2 planes * PVOX*32 halves = 55228416 B
#define Y_OFF 84861952      // NPIX*64 halves = 45056000 B  (y1 then y2)
#define PLANE_OFF 129917952 // 2 planes * PPLN*32 halves = 4602368 B
#define R1OUT_OFF 134520320 // HWPIX*128 halves = 9011200 B

// stats float sub-offsets
#define S_BN0S 0
#define S_BN0Q 32
#define S_BN1S 64
#define S_BN1Q 128
#define S_BN2S 192
#define S_BN2Q 256
#define C0A 320
#define C0B 352
#define C1A 384
#define C1B 448
#define C2A 512
#define C2B 576

// ---------------- weight pack: w[oc][ic][tap] -> per-lane MFMA B fragments ----------------
// wp index = (((tap*KH + kh)*OCT + ot)*64 + lane)*8 + j
// oc = ot*16 + (lane&15); ic = kh*32 + (lane>>4)*8 + j
__global__ void k_pack(const float* __restrict__ w, half_t* __restrict__ wp,
                       int IC, int NT, int OC) {
    int id = blockIdx.x * 256 + threadIdx.x;
    int OCT = OC >> 4, KH = IC >> 5;
    int total = NT * KH * OCT * 512;
    if (id >= total) return;
    int j = id & 7;
    int lane = (id >> 3) & 63;
    int rest = id >> 9;
    int ot = rest % OCT; rest /= OCT;
    int kh = rest % KH;
    int tap = rest / KH;
    int oc = ot * 16 + (lane & 15);
    int ic = kh * 32 + (lane >> 4) * 8 + j;
    wp[id] = (half_t)w[(oc * IC + ic) * NT + tap];
}

// ---------------- VFE: BN0 batch stats ----------------
__global__ void k_vfe_stats(const float4* __restrict__ vox, const float* __restrict__ w_lin,
                            const float* __restrict__ b_lin, float* __restrict__ S) {
    int tid = blockIdx.x * 256 + threadIdx.x;
    int c = threadIdx.x & 31;
    float4 w = ((const float4*)w_lin)[c];
    float bl = b_lin[c];
    float s = 0.f, q = 0.f;
    const int np = V_VOX * T_PTS;
    int stride = gridDim.x * 8;
    for (int p = tid >> 5; p < np; p += stride) {
        float4 v = vox[p];
        float d = v.x * w.x + v.y * w.y + v.z * w.z + v.w * w.w + bl;
        s += d;
        q += d * d;
    }
    s += __shfl_xor(s, 32);
    q += __shfl_xor(q, 32);
    if ((threadIdx.x & 63) < 32) {
        atomicAdd(&S[S_BN0S + c], s);
        atomicAdd(&S[S_BN0Q + c], q);
    }
}

// ---------------- BN finalize ----------------
__global__ void k_bn_final(const float* __restrict__ ss, const float* __restrict__ sq,
                           const float* __restrict__ g, const float* __restrict__ be,
                           float* __restrict__ ca, float* __restrict__ cb, int C, float invN) {
    int c = threadIdx.x;
    if (c >= C) return;
    float m = ss[c] * invN;
    float v = sq[c] * invN - m * m;
    float a = g[c] * rsqrtf(v + EPSV);
    ca[c] = a;
    cb[c] = be[c] - m * a;
}

// ---------------- VFE: relu(bn(h)) max over T ----------------
__global__ void k_vfe_max(const float4* __restrict__ vox, const float* __restrict__ w_lin,
                          const float* __restrict__ b_lin, const float* __restrict__ ca,
                          const float* __restrict__ cb, float* __restrict__ feats) {
    int id = blockIdx.x * 256 + threadIdx.x;
    if (id >= V_VOX * 32) return;
    int c = id & 31;
    int v = id >> 5;
    float4 w = ((const float4*)w_lin)[c];
    float bl = b_lin[c], A = ca[c], B = cb[c];
    float m = 0.f;
    for (int t = 0; t < T_PTS; t++) {
        float4 p = vox[v * T_PTS + t];
        float d = p.x * w.x + p.y * w.y + p.z * w.z + p.w * w.w + bl;
        m = fmaxf(m, A * d + B);
    }
    feats[id] = m;
}

// ---------------- scatter feats into padded channel-last f16 volume ----------------
__global__ void k_scatter(const float* __restrict__ feats, const int* __restrict__ coords,
                          half_t* __restrict__ volp) {
    int id = blockIdx.x * 256 + threadIdx.x;
    if (id >= V_VOX * 32) return;
    int c = id & 31;
    int v = id >> 5;
    int z = coords[v * 3 + 0];
    int y = coords[v * 3 + 1];
    int x = coords[v * 3 + 2];
    volp[(((z + 1) * HP + (y + 1)) * WP + (x + 1)) * 32 + c] = (half_t)feats[id];
}

// ---------------- persistent z-walk implicit-GEMM conv via MFMA f16 ----------------
// Block: 256 thr / 4 waves; tile 16x * 8y * 32oc (2 octiles via grid.z); block walks
// ALL 10 output z. Input planes (10 rows x 18 px x 32ch per kh, XOR-swizzled) live in
// a 3-slot LDS ring: each z-step stages ONE new plane (each plane staged once per
// block, 3x less than z-split blocks) then computes 216 MFMA/wave (3dz x KH x 3dx x
// 3dy x 2m x 2n) between one barrier pair. Reg-staging so both ds_write and ds_read
// carry the same XOR swizzle (byte ^= (pix&6)<<3 -> even bank spread for b128 ops).
// BN stats accumulate in registers across z-steps; atomics once at kernel end.
template <int KH, bool TWOD, int OCTT, bool RELU, bool STATS>
__global__ __launch_bounds__(256, 4) void k_conv(const half_t* __restrict__ in,
                                                 size_t khstride,
                                                 const half_t* __restrict__ wp,
                                                 const float* __restrict__ bias,
                                                 half_t* __restrict__ out,
                                                 float* __restrict__ ssum,
                                                 float* __restrict__ ssq) {
    constexpr int OC = OCTT * 16;
    constexpr int NSLOT = TWOD ? 1 : 3;
    constexpr int SLAB = 10 * 18 * 32;          // 5760 halves per (slot,kh)
    __shared__ __align__(16) half_t ring[NSLOT][KH][SLAB];

    const int tid = threadIdx.x;
    const int lane = tid & 63;
    const int wv = tid >> 6;
    const int x0 = blockIdx.x * 16;             // 11*16 = 176 exact
    const int y0b = blockIdx.y * 8;             // 25*8  = 200 exact
    const int ocb = blockIdx.z * 2;             // 2 octiles per block
    const int wrow = wv * 2;                    // wave's first out row in tile
    const int colc = lane & 15, grp = lane >> 4;

    // ---- staging address precompute (3 x 16B chunks per thread per slab) ----
    // chunk c: pix = c>>2 (row*18+px), q = c&3; 720 chunks per slab.
    int gofs[3]; int loff[3]; bool okc[3];
#pragma unroll
    for (int k = 0; k < 3; ++k) {
        int c = tid + k * 256;
        okc[k] = (c < 720);
        int cc = okc[k] ? c : 0;
        int q = cc & 3, pix = cc >> 2;
        int row = pix / 18, px = pix - row * 18;
        gofs[k] = ((y0b + row) * WP + x0 + px) * 32 + q * 8;   // halves (plane-rel)
        loff[k] = (cc * 16) ^ ((pix & 6) << 3);                // bytes (swizzled)
    }

    // stage padded plane p (all kh) into ring slot p%3 (reg round-trip)
    auto PL = [&](int p) {
#pragma unroll
        for (int kh = 0; kh < KH; ++kh) {
            const half_t* pb = in + (size_t)kh * khstride
                               + (TWOD ? (size_t)0 : (size_t)p * PPLN * 32);
            char* lb = (char*)&ring[TWOD ? 0 : (p % 3)][kh][0];
            f16x8 v0, v1, v2;
            if (okc[0]) v0 = *(const f16x8*)(pb + gofs[0]);
            if (okc[1]) v1 = *(const f16x8*)(pb + gofs[1]);
            if (okc[2]) v2 = *(const f16x8*)(pb + gofs[2]);
            if (okc[0]) *(f16x8*)(lb + loff[0]) = v0;
            if (okc[1]) *(f16x8*)(lb + loff[1]) = v1;
            if (okc[2]) *(f16x8*)(lb + loff[2]) = v2;
        }
    };

    float sreg[2] = {0.f, 0.f}, qreg[2] = {0.f, 0.f};
    const int NOZ = TWOD ? 1 : DD;

    if (!TWOD) { PL(0); PL(1); }

#pragma unroll 1
    for (int oz = 0; oz < NOZ; ++oz) {
        PL(TWOD ? 0 : oz + 2);
        __syncthreads();

        f32x4 acc[2][2];
#pragma unroll
        for (int m = 0; m < 2; ++m)
#pragma unroll
            for (int n = 0; n < 2; ++n) acc[m][n] = (f32x4)(0.f);

        // compute: sum over dz (3 or 1) and kh of 36-MFMA slab contributions
#pragma unroll
        for (int dz = 0; dz < (TWOD ? 1 : 3); ++dz) {
#pragma unroll
            for (int kh = 0; kh < KH; ++kh) {
                const char* lb = (const char*)&ring[TWOD ? 0 : ((oz + dz) % 3)][kh][0];
#pragma unroll
                for (int dx = 0; dx < 3; ++dx) {
                    f16x8 Af[4];
#pragma unroll
                    for (int r = 0; r < 4; ++r) {
                        int pix = (wrow + r) * 18 + colc + dx;
                        int ph = (pix * 64 + grp * 16) ^ ((pix & 6) << 3);
                        Af[r] = *(const f16x8*)(lb + ph);
                    }
#pragma unroll
                    for (int dy = 0; dy < 3; ++dy) {
                        f16x8 Bf[2];
#pragma unroll
                        for (int n = 0; n < 2; ++n)
                            Bf[n] = *(const f16x8*)(wp
                                + (((size_t)(dz * 9 + dy * 3 + dx) * KH + kh) * OCTT
                                   + ocb + n) * 512 + lane * 8);
#pragma unroll
                        for (int m = 0; m < 2; ++m)
#pragma unroll
                            for (int n = 0; n < 2; ++n)
                                acc[m][n] = __builtin_amdgcn_mfma_f32_16x16x32_f16(
                                    Af[dy + m], Bf[n], acc[m][n], 0, 0, 0);
                    }
                }
            }
        }

        // epilogue for this z: C/D layout col=lane&15 (oc), row=(lane>>4)*4+i (x)
#pragma unroll
        for (int n = 0; n < 2; ++n) {
            int oc = (ocb + n) * 16 + colc;
            float bv = bias[oc];
#pragma unroll
            for (int m = 0; m < 2; ++m) {
                int yy = y0b + wrow + m;
#pragma unroll
                for (int i = 0; i < 4; ++i) {
                    int xx = x0 + grp * 4 + i;
                    float v = acc[m][n][i] + bv;
                    if (STATS) { sreg[n] += v; qreg[n] += v * v; }
                    float w = RELU ? fmaxf(v, 0.f) : v;
                    out[((size_t)(oz * HH + yy) * WW + xx) * OC + oc] = (half_t)w;
                }
            }
        }
        __syncthreads();   // ring reads done before next PL overwrites slot oz%3
    }

    if (STATS) {
#pragma unroll
        for (int n = 0; n < 2; ++n) {
            float s = sreg[n], q = qreg[n];
            s += __shfl_xor(s, 16); s += __shfl_xor(s, 32);
            q += __shfl_xor(q, 16); q += __shfl_xor(q, 32);
            if (lane < 16) {
                int oc = (ocb + n) * 16 + colc;
                atomicAdd(&ssum[oc], s);
                atomicAdd(&ssq[oc], q);
            }
        }
    }
}

// ---------------- activate: x1p = relu(a*y1+b) into 2x 32-ch padded planes ----------------
__global__ void k_activate(const half_t* __restrict__ y1, const float* __restrict__ ca,
                           const float* __restrict__ cb, half_t* __restrict__ xp) {
    int id = blockIdx.x * 256 + threadIdx.x;
    if (id >= PVOX * 8) return;
    int c0 = (id & 7) * 8;
    int pix = id >> 3;
    int zp = pix / PPLN;
    int rem = pix - zp * PPLN;
    int yp = rem / WP;
    int xq = rem - yp * WP;
    f16x8 o;
    if (zp >= 1 && zp <= DD && yp >= 1 && yp <= HH && xq >= 1 && xq <= WW) {
        size_t p = ((size_t)((zp - 1) * HH + (yp - 1)) * WW + (xq - 1));
        f16x8 v = *(const f16x8*)(y1 + p * 64 + c0);
#pragma unroll
        for (int j = 0; j < 8; j++)
            o[j] = (half_t)fmaxf(ca[c0 + j] * (float)v[j] + cb[c0 + j], 0.f);
    } else {
#pragma unroll
        for (int j = 0; j < 8; j++) o[j] = (half_t)0.f;
    }
    int khp = c0 >> 5;
    *(f16x8*)(xp + (size_t)khp * PVOX * 32 + (size_t)pix * 32 + (c0 & 31)) = o;
}

// ---------------- BN2 + relu + depth mean -> 2x 32-ch padded planes ----------------
__global__ void k_depthmean(const half_t* __restrict__ y2, const float* __restrict__ ca,
                            const float* __restrict__ cb, half_t* __restrict__ plane) {
    int id = blockIdx.x * 256 + threadIdx.x;  // PPLN*64 = 2301184, divisible by 256
    int c = id & 63;
    int pix = id >> 6;
    int yp = pix / WP;
    int xq = pix - yp * WP;
    float val = 0.f;
    if (yp >= 1 && yp <= HH && xq >= 1 && xq <= WW) {
        float A = ca[c], B = cb[c], s = 0.f;
        const half_t* base = y2 + ((size_t)(yp - 1) * WW + (xq - 1)) * 64 + c;
#pragma unroll
        for (int z = 0; z < DD; z++)
            s += fmaxf(A * (float)base[(size_t)z * HWPIX * 64] + B, 0.f);
        val = s * 0.1f;
    }
    int khp = c >> 5;
    plane[(size_t)khp * PPLN * 32 + (size_t)pix * 32 + (c & 31)] = (half_t)val;
}

// ---------------- 1x1 conv 128->8 + box transforms ----------------
__global__ void k_r2(const half_t* __restrict__ r1o, const float* __restrict__ w,
                     const float* __restrict__ bias, float* __restrict__ outp) {
    __shared__ float wsm[1024];
    for (int i = threadIdx.x; i < 1024; i += 256) wsm[i] = w[i];
    __syncthreads();
    int p = blockIdx.x * 256 + threadIdx.x;
    if (p >= HWPIX) return;
    float acc[8];
#pragma unroll
    for (int o = 0; o < 8; o++) acc[o] = bias[o];
    const half_t* rb = r1o + (size_t)p * 128;
#pragma unroll 4
    for (int icb = 0; icb < 128; icb += 8) {
        f16x8 v = *(const f16x8*)(rb + icb);
#pragma unroll
        for (int j = 0; j < 8; j++) {
            float vv = (float)v[j];
#pragma unroll
            for (int o = 0; o < 8; o++) acc[o] += vv * wsm[o * 128 + icb + j];
        }
    }
    outp[0 * HWPIX + p] = acc[0];
    outp[1 * HWPIX + p] = acc[1];
    outp[2 * HWPIX + p] = acc[2];
    outp[3 * HWPIX + p] = expf(acc[3]);
    outp[4 * HWPIX + p] = expf(acc[4]);
    outp[5 * HWPIX + p] = expf(acc[5]);
    outp[6 * HWPIX + p] = tanhf(acc[6]);
    outp[7 * HWPIX + p] = 1.f / (1.f + expf(-acc[7]));
}

// ---------------- host launch ----------------
extern "C" void kernel_launch(void* const* d_in, const int* in_sizes, int n_in,
                              void* d_out, int out_size, void* d_ws, size_t ws_size,
                              hipStream_t stream) {
    const float4* voxels = (const float4*)d_in[0];
    const int* coords = (const int*)d_in[1];
    const float* w_lin = (const float*)d_in[2];
    const float* b_lin = (const float*)d_in[3];
    const float* g_bn0 = (const float*)d_in[4];
    const float* be_bn0 = (const float*)d_in[5];
    const float* w_c3a = (const float*)d_in[6];
    const float* b_c3a = (const float*)d_in[7];
    const float* g_bn1 = (const float*)d_in[8];
    const float* be_bn1 = (const float*)d_in[9];
    const float* w_c3b = (const float*)d_in[10];
    const float* b_c3b = (const float*)d_in[11];
    const float* g_bn2 = (const float*)d_in[12];
    const float* be_bn2 = (const float*)d_in[13];
    const float* w_r1 = (const float*)d_in[14];
    const float* b_r1 = (const float*)d_in[15];
    const float* w_r2 = (const float*)d_in[16];
    const float* b_r2 = (const float*)d_in[17];

    char* ws = (char*)d_ws;
    half_t* wpA = (half_t*)(ws + WPA_OFF);
    half_t* wpB = (half_t*)(ws + WPB_OFF);
    half_t* wpR1 = (half_t*)(ws + WPR1_OFF);
    float* S = (float*)(ws + STATS_OFF);
    float* feats = (float*)(ws + FEATS_OFF);
    half_t* volp = (half_t*)(ws + VOLP_OFF);
    half_t* x1p = (half_t*)(ws + X1P_OFF);
    half_t* Y = (half_t*)(ws + Y_OFF);
    half_t* plane = (half_t*)(ws + PLANE_OFF);
    half_t* r1out = (half_t*)(ws + R1OUT_OFF);
    float* outp = (float*)d_out;

    hipMemsetAsync(S, 0, 320 * sizeof(float), stream);
    hipMemsetAsync(volp, 0, (size_t)PVOX * 32 * sizeof(half_t), stream);

    // weight packs
    k_pack<<<216, 256, 0, stream>>>(w_c3a, wpA, 32, 27, 64);
    k_pack<<<432, 256, 0, stream>>>(w_c3b, wpB, 64, 27, 64);
    k_pack<<<288, 256, 0, stream>>>(w_r1, wpR1, 64, 9, 128);

    // VFE
    k_vfe_stats<<<512, 256, 0, stream>>>(voxels, w_lin, b_lin, S);
    k_bn_final<<<1, 64, 0, stream>>>(S + S_BN0S, S + S_BN0Q, g_bn0, be_bn0,
                                     S + C0A, S + C0B, 32, 1.f / 420000.f);
    k_vfe_max<<<1500, 256, 0, stream>>>(voxels, w_lin, b_lin, S + C0A, S + C0B, feats);
    k_scatter<<<1500, 256, 0, stream>>>(feats, coords, volp);

    // conv3a (IC=32): z-walk, 16x8 tiles, oc split in 2 -> y1 f16 [p][64], fused BN1 stats
    k_conv<1, false, 4, false, true><<<dim3(11, 25, 2), 256, 0, stream>>>(
        volp, 0, wpA, b_c3a, Y, S + S_BN1S, S + S_BN1Q);
    k_bn_final<<<1, 64, 0, stream>>>(S + S_BN1S, S + S_BN1Q, g_bn1, be_bn1,
                                     S + C1A, S + C1B, 64, 1.f / 352000.f);
    k_activate<<<13484, 256, 0, stream>>>(Y, S + C1A, S + C1B, x1p);

    // conv3b (IC=64 as 2x32-ch planes): z-walk -> y2 f16 [p][64], fused BN2 stats
    k_conv<2, false, 4, false, true><<<dim3(11, 25, 2), 256, 0, stream>>>(
        x1p, (size_t)PVOX * 32, wpB, b_c3b, Y, S + S_BN2S, S + S_BN2Q);
    k_bn_final<<<1, 64, 0, stream>>>(S + S_BN2S, S + S_BN2Q, g_bn2, be_bn2,
                                     S + C2A, S + C2B, 64, 1.f / 352000.f);

    // BN2+relu+depth-mean -> 2x 32-ch padded planes
    k_depthmean<<<8989, 256, 0, stream>>>(Y, S + C2A, S + C2B, plane);

    // RPN: r1 (2D conv via TWOD template, 128 oc -> grid.z=4 oc-pairs) + relu
    k_conv<2, true, 8, true, false><<<dim3(11, 25, 4), 256, 0, stream>>>(
        plane, (size_t)PPLN * 32, wpR1, b_r1, r1out, nullptr, nullptr);
    k_r2<<<138, 256, 0, stream>>>(r1out, w_r2, b_r2, outp);
}

// Round 15
// 468.436 us; speedup vs baseline: 1.2435x; 1.2435x over previous
//
#include <hip/hip_runtime.h>
#include <math.h>

// ---------------- problem constants ----------------
#define V_VOX 12000
#define T_PTS 35
#define DD 10
#define HH 200
#define WW 176
#define EPSV 1e-5f

#define DP 12
#define HP 202
#define WP 178
#define PPLN (HP * WP)          // 35956 padded plane pixels
#define PVOX (DP * PPLN)        // 431472 padded volume pixels
#define NPIX (DD * HH * WW)     // 352000
#define HWPIX (HH * WW)         // 35200

typedef _Float16 half_t;
typedef _Float16 f16x8 __attribute__((ext_vector_type(8)));
typedef float f32x16 __attribute__((ext_vector_type(16)));

// ---------------- workspace layout (BYTE offsets, all 256-aligned) ----------------
#define WPA_OFF 0           // 27*1*2*2*512 halves = 110592 B
#define WPB_OFF 110592      // 27*2*2*2*512 halves = 221184 B
#define WPR1_OFF 331776     // 9*2*2*4*512 halves = 147456 B
#define STATS_OFF 479232    // 1024 floats
#define FEATS_OFF 483328    // 12000*32 f32 = 1536000 B
#define VOLP_OFF 2019328    // PVOX*32 halves = 27614208 B
#define X1P_OFF 29633536    // 2 planes * PVOX*32 halves = 55228416 B
#define Y_OFF 84861952      // NPIX*64 halves = 45056000 B  (y1 then y2)
#define PLANE_OFF 129917952 // 2 planes * PPLN*32 halves = 4602368 B
#define R1OUT_OFF 134520320 // HWPIX*128 halves = 9011200 B

// stats float sub-offsets
#define S_BN0S 0
#define S_BN0Q 32
#define S_BN1S 64
#define S_BN1Q 128
#define S_BN2S 192
#define S_BN2Q 256
#define C0A 320
#define C0B 352
#define C1A 384
#define C1B 448
#define C2A 512
#define C2B 576

// ---------------- global_load_lds helper (width 16, gfx950) ----------------
__device__ __forceinline__ void gload16(const half_t* g, half_t* l) {
    __builtin_amdgcn_global_load_lds(
        (const __attribute__((address_space(1))) void*)g,
        (__attribute__((address_space(3))) void*)l, 16, 0, 0);
}

// ---------------- weight pack for 32-wide octiles (mfma 32x32x16 B fragments) ----
// wp idx = ((((tap*KH + kh)*2 + khf)*OCT + ot)*64 + lane)*8 + j
// oc = ot*32 + (lane&31); ic = kh*32 + khf*16 + (lane>>5)*8 + j
__global__ void k_pack(const float* __restrict__ w, half_t* __restrict__ wp,
                       int IC, int NT, int OC) {
    int id = blockIdx.x * 256 + threadIdx.x;
    int OCT = OC >> 5, KH = IC >> 5;
    int total = NT * KH * 2 * OCT * 512;
    if (id >= total) return;
    int j = id & 7;
    int lane = (id >> 3) & 63;
    int rest = id >> 9;
    int ot = rest % OCT; rest /= OCT;
    int khf = rest & 1; rest >>= 1;
    int kh = rest % KH;
    int tap = rest / KH;
    int oc = ot * 32 + (lane & 31);
    int ic = kh * 32 + khf * 16 + (lane >> 5) * 8 + j;
    wp[id] = (half_t)w[(oc * IC + ic) * NT + tap];
}

// ---------------- VFE: BN0 batch stats ----------------
__global__ void k_vfe_stats(const float4* __restrict__ vox, const float* __restrict__ w_lin,
                            const float* __restrict__ b_lin, float* __restrict__ S) {
    int tid = blockIdx.x * 256 + threadIdx.x;
    int c = threadIdx.x & 31;
    float4 w = ((const float4*)w_lin)[c];
    float bl = b_lin[c];
    float s = 0.f, q = 0.f;
    const int np = V_VOX * T_PTS;
    int stride = gridDim.x * 8;
    for (int p = tid >> 5; p < np; p += stride) {
        float4 v = vox[p];
        float d = v.x * w.x + v.y * w.y + v.z * w.z + v.w * w.w + bl;
        s += d;
        q += d * d;
    }
    s += __shfl_xor(s, 32);
    q += __shfl_xor(q, 32);
    if ((threadIdx.x & 63) < 32) {
        atomicAdd(&S[S_BN0S + c], s);
        atomicAdd(&S[S_BN0Q + c], q);
    }
}

// ---------------- BN finalize ----------------
__global__ void k_bn_final(const float* __restrict__ ss, const float* __restrict__ sq,
                           const float* __restrict__ g, const float* __restrict__ be,
                           float* __restrict__ ca, float* __restrict__ cb, int C, float invN) {
    int c = threadIdx.x;
    if (c >= C) return;
    float m = ss[c] * invN;
    float v = sq[c] * invN - m * m;
    float a = g[c] * rsqrtf(v + EPSV);
    ca[c] = a;
    cb[c] = be[c] - m * a;
}

// ---------------- VFE: relu(bn(h)) max over T ----------------
__global__ void k_vfe_max(const float4* __restrict__ vox, const float* __restrict__ w_lin,
                          const float* __restrict__ b_lin, const float* __restrict__ ca,
                          const float* __restrict__ cb, float* __restrict__ feats) {
    int id = blockIdx.x * 256 + threadIdx.x;
    if (id >= V_VOX * 32) return;
    int c = id & 31;
    int v = id >> 5;
    float4 w = ((const float4*)w_lin)[c];
    float bl = b_lin[c], A = ca[c], B = cb[c];
    float m = 0.f;
    for (int t = 0; t < T_PTS; t++) {
        float4 p = vox[v * T_PTS + t];
        float d = p.x * w.x + p.y * w.y + p.z * w.z + p.w * w.w + bl;
        m = fmaxf(m, A * d + B);
    }
    feats[id] = m;
}

// ---------------- scatter feats into padded channel-last f16 volume ----------------
__global__ void k_scatter(const float* __restrict__ feats, const int* __restrict__ coords,
                          half_t* __restrict__ volp) {
    int id = blockIdx.x * 256 + threadIdx.x;
    if (id >= V_VOX * 32) return;
    int c = id & 31;
    int v = id >> 5;
    int z = coords[v * 3 + 0];
    int y = coords[v * 3 + 1];
    int x = coords[v * 3 + 2];
    volp[(((z + 1) * HP + (y + 1)) * WP + (x + 1)) * 32 + c] = (half_t)feats[id];
}

// ---------------- implicit-GEMM conv via MFMA f32_32x32x16_f16 ----------------
// Block: 512 thr / 8 waves = (yg 0..3) x (og 0..1); tile 16x * 16y * 64oc.
// Wave owns 4 rows x 32 oc; acc = 2 x f32x16 (32 VGPR). Fragment = 16x*2y pixels:
// A lane map: row=(l&31)=yr*16+x, k=(l>>5)*8+j.  B: col=l&31 (oc), k=(l>>5)*8+j.
// C/D: col=lane&31, row=(reg&3)+8*(reg>>2)+4*(lane>>5)  [HW-verified m74/m101].
// Per slab (dz,kh): stage A 18x18x32ch (20.7KB, gload_lds linear dest + inverse-
// XOR-swizzled global source; read swizzle byte^=(p&7)<<4) + B 36KB (contiguous),
// vmcnt(0)+syncthreads drain (r9-proven), then 36 fat MFMA/wave.
// LDS 57.6KB -> 2 blocks/CU = 16 waves/CU at VGPR<=128 (launch_bounds 512,4).
template <int KH, int DZ, int OCALL, bool RELU, bool STATS>
__global__ __launch_bounds__(512, 4) void k_conv(const half_t* __restrict__ in,
                                                 size_t khstride,
                                                 const half_t* __restrict__ wp,
                                                 const float* __restrict__ bias,
                                                 half_t* __restrict__ out,
                                                 float* __restrict__ ssum,
                                                 float* __restrict__ ssq) {
    constexpr int OCT = OCALL / 32;
    constexpr int NS = DZ * KH;
    __shared__ __align__(16) half_t tA[1296 * 8];   // 20736 B
    __shared__ __align__(16) half_t tB[36 * 512];   // 36864 B

    const int tid = threadIdx.x;
    const int lane = tid & 63;
    const int wv = tid >> 6;
    const int yg = wv >> 1;           // 0..3: wave's 4-row group
    const int og = wv & 1;            // 0..1: wave's 32-oc octile
    const int x0 = blockIdx.x * 16;
    const int y0b = blockIdx.y * 16;
    const int bz = blockIdx.z;
    const int z0 = (DZ == 3) ? bz : 0;
    const int ocb = (DZ == 3) ? 0 : bz * 2;          // octile-of-32 base
    const bool valid = (y0b + yg * 4 < HH);
    const int xl = lane & 15;
    const int yrl = (lane >> 4) & 1;
    const int kg = (lane >> 5) & 1;

    // ---- A-stage inverse-swizzle decode (slab-invariant). Phys chunk c holds
    // logical (p,q) with phys_byte=(p*64+q*16)^((p&7)<<4):
    //   p0=((c>>2)^(c>>4))&1 ; p=((c>>3)<<1)|p0 ; q=(c&3)^(p&3)
    int gofsA[3]; bool okA[3];
#pragma unroll
    for (int r = 0; r < 3; ++r) {
        int c = tid + r * 512;
        okA[r] = (c < 1296);
        int cc = okA[r] ? c : 0;
        int p0 = ((cc >> 2) ^ (cc >> 4)) & 1;
        int p = ((cc >> 3) << 1) | p0;
        int q = (cc & 3) ^ (p & 3);
        int row = p / 18, px = p - row * 18;
        int grow = y0b + row;
        if (grow > HP - 1) grow = HP - 1;   // clamp; pad rows are zero
        gofsA[r] = (grow * WP + x0 + px) * 32 + q * 8;
    }

    f32x16 acc[2];
#pragma unroll
    for (int m = 0; m < 2; ++m) acc[m] = (f32x16)(0.f);

    auto STAGE = [&](int s) {
        const int dz = s / KH, kh = s % KH;
        const half_t* sl = in + (size_t)kh * khstride
                           + (size_t)(z0 + dz) * (DZ == 3 ? (size_t)PPLN * 32 : 0);
#pragma unroll
        for (int r = 0; r < 3; ++r)
            if (okA[r]) gload16(sl + gofsA[r], &tA[(size_t)(tid + r * 512) * 8]);
#pragma unroll
        for (int r = 0; r < 5; ++r) {
            int c = tid + r * 512;
            if (c < 2304) {
                int u = c >> 6;                    // wave-uniform unit id
                int tl = u >> 2, khf = (u >> 1) & 1, ot = u & 1;
                const half_t* g = wp + ((((size_t)(dz * 9 + tl) * KH + kh) * 2 + khf) * OCT
                                        + ocb + ot) * 512 + lane * 8;
                gload16(g, &tB[(size_t)u * 512 + lane * 8]);
            }
        }
    };

#pragma unroll 1
    for (int s = 0; s < NS; ++s) {
        STAGE(s);
        asm volatile("s_waitcnt vmcnt(0)" ::: "memory");
        __syncthreads();

        if (valid) {
#pragma unroll
            for (int khalf = 0; khalf < 2; ++khalf) {
#pragma unroll
                for (int dx = 0; dx < 3; ++dx) {
#pragma unroll
                    for (int dy = 0; dy < 3; ++dy) {
                        int u = ((dy * 3 + dx) * 2 + khalf) * 2 + og;
                        f16x8 Bf = *(const f16x8*)&tB[u * 512 + lane * 8];
#pragma unroll
                        for (int m = 0; m < 2; ++m) {
                            int p = (yg * 4 + dy + 2 * m + yrl) * 18 + dx + xl;
                            int ph = ((p << 6) | ((khalf * 2 + kg) << 4)) ^ ((p & 7) << 4);
                            f16x8 Af = *(const f16x8*)((const char*)tA + ph);
                            acc[m] = __builtin_amdgcn_mfma_f32_32x32x16_f16(
                                Af, Bf, acc[m], 0, 0, 0);
                        }
                    }
                }
            }
        }
        __syncthreads();
    }

    if (!valid) return;
    // epilogue: C/D col=lane&31 (oc); row rp=(reg&3)+8*(reg>>2)+4*kg -> x=rp&15, yr=rp>>4
    float sreg = 0.f, qreg = 0.f;
    int oc = (ocb + og) * 32 + (lane & 31);
    float bv = bias[oc];
#pragma unroll
    for (int m = 0; m < 2; ++m) {
#pragma unroll
        for (int reg = 0; reg < 16; ++reg) {
            int rp = (reg & 3) + 8 * (reg >> 2) + 4 * kg;
            int xx = x0 + (rp & 15);
            int yy = y0b + yg * 4 + 2 * m + (rp >> 4);
            float v = acc[m][reg] + bv;
            if (STATS) { sreg += v; qreg += v * v; }
            float w = RELU ? fmaxf(v, 0.f) : v;
            out[((size_t)(z0 * HH + yy) * WW + xx) * OCALL + oc] = (half_t)w;
        }
    }
    if (STATS) {
        sreg += __shfl_xor(sreg, 32);
        qreg += __shfl_xor(qreg, 32);
        if (lane < 32) {
            atomicAdd(&ssum[oc], sreg);
            atomicAdd(&ssq[oc], qreg);
        }
    }
}

// ---------------- activate: x1p = relu(a*y1+b) into 2x 32-ch padded planes ----------------
__global__ void k_activate(const half_t* __restrict__ y1, const float* __restrict__ ca,
                           const float* __restrict__ cb, half_t* __restrict__ xp) {
    int id = blockIdx.x * 256 + threadIdx.x;
    if (id >= PVOX * 8) return;
    int c0 = (id & 7) * 8;
    int pix = id >> 3;
    int zp = pix / PPLN;
    int rem = pix - zp * PPLN;
    int yp = rem / WP;
    int xq = rem - yp * WP;
    f16x8 o;
    if (zp >= 1 && zp <= DD && yp >= 1 && yp <= HH && xq >= 1 && xq <= WW) {
        size_t p = ((size_t)((zp - 1) * HH + (yp - 1)) * WW + (xq - 1));
        f16x8 v = *(const f16x8*)(y1 + p * 64 + c0);
#pragma unroll
        for (int j = 0; j < 8; j++)
            o[j] = (half_t)fmaxf(ca[c0 + j] * (float)v[j] + cb[c0 + j], 0.f);
    } else {
#pragma unroll
        for (int j = 0; j < 8; j++) o[j] = (half_t)0.f;
    }
    int khp = c0 >> 5;
    *(f16x8*)(xp + (size_t)khp * PVOX * 32 + (size_t)pix * 32 + (c0 & 31)) = o;
}

// ---------------- BN2 + relu + depth mean -> 2x 32-ch padded planes ----------------
__global__ void k_depthmean(const half_t* __restrict__ y2, const float* __restrict__ ca,
                            const float* __restrict__ cb, half_t* __restrict__ plane) {
    int id = blockIdx.x * 256 + threadIdx.x;  // PPLN*64 = 2301184, divisible by 256
    int c = id & 63;
    int pix = id >> 6;
    int yp = pix / WP;
    int xq = pix - yp * WP;
    float val = 0.f;
    if (yp >= 1 && yp <= HH && xq >= 1 && xq <= WW) {
        float A = ca[c], B = cb[c], s = 0.f;
        const half_t* base = y2 + ((size_t)(yp - 1) * WW + (xq - 1)) * 64 + c;
#pragma unroll
        for (int z = 0; z < DD; z++)
            s += fmaxf(A * (float)base[(size_t)z * HWPIX * 64] + B, 0.f);
        val = s * 0.1f;
    }
    int khp = c >> 5;
    plane[(size_t)khp * PPLN * 32 + (size_t)pix * 32 + (c & 31)] = (half_t)val;
}

// ---------------- 1x1 conv 128->8 + box transforms ----------------
__global__ void k_r2(const half_t* __restrict__ r1o, const float* __restrict__ w,
                     const float* __restrict__ bias, float* __restrict__ outp) {
    __shared__ float wsm[1024];
    for (int i = threadIdx.x; i < 1024; i += 256) wsm[i] = w[i];
    __syncthreads();
    int p = blockIdx.x * 256 + threadIdx.x;
    if (p >= HWPIX) return;
    float acc[8];
#pragma unroll
    for (int o = 0; o < 8; o++) acc[o] = bias[o];
    const half_t* rb = r1o + (size_t)p * 128;
#pragma unroll 4
    for (int icb = 0; icb < 128; icb += 8) {
        f16x8 v = *(const f16x8*)(rb + icb);
#pragma unroll
        for (int j = 0; j < 8; j++) {
            float vv = (float)v[j];
#pragma unroll
            for (int o = 0; o < 8; o++) acc[o] += vv * wsm[o * 128 + icb + j];
        }
    }
    outp[0 * HWPIX + p] = acc[0];
    outp[1 * HWPIX + p] = acc[1];
    outp[2 * HWPIX + p] = acc[2];
    outp[3 * HWPIX + p] = expf(acc[3]);
    outp[4 * HWPIX + p] = expf(acc[4]);
    outp[5 * HWPIX + p] = expf(acc[5]);
    outp[6 * HWPIX + p] = tanhf(acc[6]);
    outp[7 * HWPIX + p] = 1.f / (1.f + expf(-acc[7]));
}

// ---------------- host launch ----------------
extern "C" void kernel_launch(void* const* d_in, const int* in_sizes, int n_in,
                              void* d_out, int out_size, void* d_ws, size_t ws_size,
                              hipStream_t stream) {
    const float4* voxels = (const float4*)d_in[0];
    const int* coords = (const int*)d_in[1];
    const float* w_lin = (const float*)d_in[2];
    const float* b_lin = (const float*)d_in[3];
    const float* g_bn0 = (const float*)d_in[4];
    const float* be_bn0 = (const float*)d_in[5];
    const float* w_c3a = (const float*)d_in[6];
    const float* b_c3a = (const float*)d_in[7];
    const float* g_bn1 = (const float*)d_in[8];
    const float* be_bn1 = (const float*)d_in[9];
    const float* w_c3b = (const float*)d_in[10];
    const float* b_c3b = (const float*)d_in[11];
    const float* g_bn2 = (const float*)d_in[12];
    const float* be_bn2 = (const float*)d_in[13];
    const float* w_r1 = (const float*)d_in[14];
    const float* b_r1 = (const float*)d_in[15];
    const float* w_r2 = (const float*)d_in[16];
    const float* b_r2 = (const float*)d_in[17];

    char* ws = (char*)d_ws;
    half_t* wpA = (half_t*)(ws + WPA_OFF);
    half_t* wpB = (half_t*)(ws + WPB_OFF);
    half_t* wpR1 = (half_t*)(ws + WPR1_OFF);
    float* S = (float*)(ws + STATS_OFF);
    float* feats = (float*)(ws + FEATS_OFF);
    half_t* volp = (half_t*)(ws + VOLP_OFF);
    half_t* x1p = (half_t*)(ws + X1P_OFF);
    half_t* Y = (half_t*)(ws + Y_OFF);
    half_t* plane = (half_t*)(ws + PLANE_OFF);
    half_t* r1out = (half_t*)(ws + R1OUT_OFF);
    float* outp = (float*)d_out;

    hipMemsetAsync(S, 0, 320 * sizeof(float), stream);
    hipMemsetAsync(volp, 0, (size_t)PVOX * 32 * sizeof(half_t), stream);

    // weight packs (32-wide octile fragment order)
    k_pack<<<216, 256, 0, stream>>>(w_c3a, wpA, 32, 27, 64);
    k_pack<<<432, 256, 0, stream>>>(w_c3b, wpB, 64, 27, 64);
    k_pack<<<288, 256, 0, stream>>>(w_r1, wpR1, 64, 9, 128);

    // VFE
    k_vfe_stats<<<512, 256, 0, stream>>>(voxels, w_lin, b_lin, S);
    k_bn_final<<<1, 64, 0, stream>>>(S + S_BN0S, S + S_BN0Q, g_bn0, be_bn0,
                                     S + C0A, S + C0B, 32, 1.f / 420000.f);
    k_vfe_max<<<1500, 256, 0, stream>>>(voxels, w_lin, b_lin, S + C0A, S + C0B, feats);
    k_scatter<<<1500, 256, 0, stream>>>(feats, coords, volp);

    // conv3a (IC=32) -> y1 f16 [p][64], fused BN1 stats
    k_conv<1, 3, 64, false, true><<<dim3(11, 13, 10), 512, 0, stream>>>(
        volp, 0, wpA, b_c3a, Y, S + S_BN1S, S + S_BN1Q);
    k_bn_final<<<1, 64, 0, stream>>>(S + S_BN1S, S + S_BN1Q, g_bn1, be_bn1,
                                     S + C1A, S + C1B, 64, 1.f / 352000.f);
    k_activate<<<13484, 256, 0, stream>>>(Y, S + C1A, S + C1B, x1p);

    // conv3b (IC=64 as 2x32-ch planes) -> y2 f16 [p][64], fused BN2 stats
    k_conv<2, 3, 64, false, true><<<dim3(11, 13, 10), 512, 0, stream>>>(
        x1p, (size_t)PVOX * 32, wpB, b_c3b, Y, S + S_BN2S, S + S_BN2Q);
    k_bn_final<<<1, 64, 0, stream>>>(S + S_BN2S, S + S_BN2Q, g_bn2, be_bn2,
                                     S + C2A, S + C2B, 64, 1.f / 352000.f);

    // BN2+relu+depth-mean -> 2x 32-ch padded planes
    k_depthmean<<<8989, 256, 0, stream>>>(Y, S + C2A, S + C2B, plane);

    // RPN: r1 (2D conv, 128 oc -> 2 z-groups of 2 octiles) + relu -> [p][128] f16
    k_conv<2, 1, 128, true, false><<<dim3(11, 13, 2), 512, 0, stream>>>(
        plane, (size_t)PPLN * 32, wpR1, b_r1, r1out, nullptr, nullptr);
    k_r2<<<138, 256, 0, stream>>>(r1out, w_r2, b_r2, outp);
}